// Round 1
// baseline (101.284 us; speedup 1.0000x reference)
//
#include <hip/hip_runtime.h>

// out[b,u] = sum_d x[b,d] * emb[idx[b],d,u]
// B=256, D=1024, U=1024, C=64, fp32.
//
// Grid: (64 classes) x (4 u-tiles of 256). Block: 256 threads = 4 waves.
//   - block scans content_idx, builds list of examples with idx==c (skip if none)
//   - wave w owns d-range [w*256, w*256+256); each lane owns 4 consecutive u (float4)
//   - x rows staged in LDS (chunks of up to MC=8 examples), broadcast-read
//   - emb slice read exactly once per block (1 MB), all examples accumulated together
//   - cross-wave d-reduction via LDS, plain float4 stores (no atomics, no pre-zero)

#define B_N 256
#define D_N 1024
#define U_N 1024
#define C_N 64
#define MC  8

__device__ __forceinline__ void fma4(float4& a, const float4& e, float s) {
    a.x = fmaf(e.x, s, a.x);
    a.y = fmaf(e.y, s, a.y);
    a.z = fmaf(e.z, s, a.z);
    a.w = fmaf(e.w, s, a.w);
}

__global__ __launch_bounds__(256) void content_gather_gemv(
    const int* __restrict__ idx,
    const float* __restrict__ x,
    const float* __restrict__ emb,
    float* __restrict__ out)
{
    __shared__ float  xs[MC][D_N];   // 32 KB staged x rows (zero-padded)
    __shared__ float4 red[256];      // 4 KB cross-wave reduction buffer
    __shared__ int    bs[B_N];       // example list for this class
    __shared__ int    cnt;

    const int c    = blockIdx.x;     // class 0..63
    const int ut   = blockIdx.y;     // u-tile 0..3 (256 u each)
    const int tid  = threadIdx.x;    // 0..255
    const int wave = tid >> 6;       // 0..3 -> d-quarter
    const int lane = tid & 63;       // -> 4 u's

    if (tid == 0) cnt = 0;
    __syncthreads();
    // B_N == blockDim.x: each thread tests one example
    if (idx[tid] == c) {
        int p = atomicAdd(&cnt, 1);  // order irrelevant: per-b result independent
        bs[p] = tid;
    }
    __syncthreads();
    const int M = cnt;
    if (M == 0) return;              // unused class: no emb traffic, no stores

    const int u0 = ut * 256 + lane * 4;          // this lane's first u
    const int d0 = wave * 256;                   // this wave's d-range start
    const float* ebase = emb + (((size_t)c * D_N + d0) * U_N) + u0;

    for (int base = 0; base < M; base += MC) {
        const int mc = min(MC, M - base);

        // ---- stage x rows into LDS (zero-pad unused slots) ----
        #pragma unroll
        for (int j = 0; j < MC; ++j) {
            float4 v = make_float4(0.f, 0.f, 0.f, 0.f);
            if (j < mc) {
                v = *(const float4*)(x + (size_t)bs[base + j] * D_N + tid * 4);
            }
            *(float4*)&xs[j][tid * 4] = v;
        }
        __syncthreads();

        float4 acc[MC];
        #pragma unroll
        for (int j = 0; j < MC; ++j) acc[j] = make_float4(0.f, 0.f, 0.f, 0.f);

        // ---- main loop: 256 d's per wave, 4 at a time ----
        const float* ep = ebase;
        #pragma unroll 4
        for (int dg = 0; dg < 64; ++dg) {
            float4 e0 = *(const float4*)(ep);
            float4 e1 = *(const float4*)(ep + U_N);
            float4 e2 = *(const float4*)(ep + 2 * U_N);
            float4 e3 = *(const float4*)(ep + 3 * U_N);
            ep += 4 * U_N;
            const int dx = d0 + dg * 4;
            #pragma unroll
            for (int j = 0; j < MC; ++j) {
                float4 xv = *(const float4*)&xs[j][dx];  // wave-uniform broadcast
                fma4(acc[j], e0, xv.x);
                fma4(acc[j], e1, xv.y);
                fma4(acc[j], e2, xv.z);
                fma4(acc[j], e3, xv.w);
            }
        }

        // ---- cross-wave reduction + store ----
        for (int j = 0; j < mc; ++j) {
            red[tid] = acc[j];
            __syncthreads();
            if (tid < 64) {
                float4 a0 = red[tid];
                float4 a1 = red[tid + 64];
                float4 a2 = red[tid + 128];
                float4 a3 = red[tid + 192];
                float4 s;
                s.x = (a0.x + a1.x) + (a2.x + a3.x);
                s.y = (a0.y + a1.y) + (a2.y + a3.y);
                s.z = (a0.z + a1.z) + (a2.z + a3.z);
                s.w = (a0.w + a1.w) + (a2.w + a3.w);
                *(float4*)(out + (size_t)bs[base + j] * U_N + ut * 256 + tid * 4) = s;
            }
            __syncthreads();
        }
        // trailing barrier above also protects xs re-staging for next chunk
    }
}

extern "C" void kernel_launch(void* const* d_in, const int* in_sizes, int n_in,
                              void* d_out, int out_size, void* d_ws, size_t ws_size,
                              hipStream_t stream) {
    const int*   idx = (const int*)d_in[0];
    const float* x   = (const float*)d_in[1];
    const float* emb = (const float*)d_in[2];
    float*       out = (float*)d_out;

    dim3 grid(C_N, U_N / 256);   // 64 x 4 = 256 blocks, one per CU
    dim3 block(256);
    content_gather_gemv<<<grid, block, 0, stream>>>(idx, x, emb, out);
}

// Round 2
// 46.514 us; speedup vs baseline: 2.1775x; 2.1775x over previous
//
#include <hip/hip_runtime.h>

// out[b,u] = sum_d x[b,d] * emb[idx[b],d,u]    B=256, D=1024, U=1024, C=64, fp32
//
// Grid: (64 classes) x (4 u-tiles of 256). Block: 1024 threads = 16 waves
// (4 waves/SIMD for latency hiding; __launch_bounds__(1024,4) caps VGPR at 128).
//   - block scans content_idx, builds its class's example list (skip if empty)
//   - wave w owns d-range [w*64, w*64+64); each lane owns 4 consecutive u (float4)
//   - MC=12 examples per pass -> single emb pass for essentially all classes
//     (chunk loop kept for correctness if M > 12); wave-uniform guards skip
//     dead FMA/LDS work when mc <= 4 or <= 8
//   - x rows staged in LDS, broadcast-read; emb slice read exactly once (1 MB)
//   - cross-wave reduction reuses the xs LDS region (dead after the d-loop)

#define B_N 256
#define D_N 1024
#define U_N 1024
#define C_N 64
#define MC  12
#define NW  16
#define TPB 1024

__device__ __forceinline__ void fma4(float4& a, const float4& e, float s) {
    a.x = fmaf(e.x, s, a.x);
    a.y = fmaf(e.y, s, a.y);
    a.z = fmaf(e.z, s, a.z);
    a.w = fmaf(e.w, s, a.w);
}

__global__ __launch_bounds__(TPB, 4) void content_gather_gemv(
    const int* __restrict__ idx,
    const float* __restrict__ x,
    const float* __restrict__ emb,
    float* __restrict__ out)
{
    __shared__ __align__(16) float smem[MC * D_N]; // 48 KB xs; reduction reuses front 16 KB
    __shared__ int bs[B_N];
    __shared__ int cnt;

    const int c    = blockIdx.x;     // class
    const int ut   = blockIdx.y;     // u-tile (256 u)
    const int tid  = threadIdx.x;    // 0..1023
    const int wave = tid >> 6;       // 0..15 -> d-slice of 64
    const int lane = tid & 63;       // -> 4 u's

    if (tid == 0) cnt = 0;
    __syncthreads();
    if (tid < B_N && idx[tid] == c) {
        bs[atomicAdd(&cnt, 1)] = tid;   // order irrelevant: per-b results independent
    }
    __syncthreads();
    const int M = cnt;
    if (M == 0) return;

    const int u0 = ut * 256 + lane * 4;
    const int d0 = wave * (D_N / NW);           // 64 d per wave
    const float* ebase = emb + ((size_t)c * D_N + d0) * U_N + u0;

    for (int base = 0; base < M; base += MC) {
        const int mc = min(MC, M - base);

        // ---- stage x rows into LDS (zero-pad unused slots) ----
        #pragma unroll
        for (int j = 0; j < MC; ++j) {
            float v = 0.f;
            if (j < mc) v = x[(size_t)bs[base + j] * D_N + tid];
            smem[j * D_N + tid] = v;
        }
        __syncthreads();

        float4 acc[MC];
        #pragma unroll
        for (int j = 0; j < MC; ++j) acc[j] = make_float4(0.f, 0.f, 0.f, 0.f);

        const bool m4 = (mc > 4);   // block-uniform
        const bool m8 = (mc > 8);

        // ---- main loop: 64 d per wave, 4 rows per iteration ----
        const float* ep = ebase;
        for (int dg = 0; dg < (D_N / NW) / 4; ++dg) {   // 16 iterations
            float4 e0 = *(const float4*)(ep);
            float4 e1 = *(const float4*)(ep + U_N);
            float4 e2 = *(const float4*)(ep + 2 * U_N);
            float4 e3 = *(const float4*)(ep + 3 * U_N);
            ep += 4 * U_N;
            const int dx = d0 + dg * 4;

            #pragma unroll
            for (int j = 0; j < 4; ++j) {
                float4 xv = *(const float4*)&smem[j * D_N + dx];  // broadcast
                fma4(acc[j], e0, xv.x); fma4(acc[j], e1, xv.y);
                fma4(acc[j], e2, xv.z); fma4(acc[j], e3, xv.w);
            }
            if (m4) {
                #pragma unroll
                for (int j = 4; j < 8; ++j) {
                    float4 xv = *(const float4*)&smem[j * D_N + dx];
                    fma4(acc[j], e0, xv.x); fma4(acc[j], e1, xv.y);
                    fma4(acc[j], e2, xv.z); fma4(acc[j], e3, xv.w);
                }
            }
            if (m8) {
                #pragma unroll
                for (int j = 8; j < MC; ++j) {
                    float4 xv = *(const float4*)&smem[j * D_N + dx];
                    fma4(acc[j], e0, xv.x); fma4(acc[j], e1, xv.y);
                    fma4(acc[j], e2, xv.z); fma4(acc[j], e3, xv.w);
                }
            }
        }

        __syncthreads();   // xs dead from here; reuse smem as reduction buffer

        float4* red = (float4*)smem;   // 1024 float4 = 16 KB
        #pragma unroll
        for (int j = 0; j < MC; ++j) {
            if (j < mc) {              // block-uniform -> barriers legal inside
                red[tid] = acc[j];     // j compile-time: acc stays in registers
                __syncthreads();
                if (tid < 64) {
                    float4 s = red[tid];
                    #pragma unroll
                    for (int w = 1; w < NW; ++w) {
                        float4 a = red[w * 64 + tid];
                        s.x += a.x; s.y += a.y; s.z += a.z; s.w += a.w;
                    }
                    *(float4*)(out + (size_t)bs[base + j] * U_N + ut * 256 + tid * 4) = s;
                }
                __syncthreads();
            }
        }
        __syncthreads();   // protect xs restage if another chunk follows
    }
}

extern "C" void kernel_launch(void* const* d_in, const int* in_sizes, int n_in,
                              void* d_out, int out_size, void* d_ws, size_t ws_size,
                              hipStream_t stream) {
    const int*   idx = (const int*)d_in[0];
    const float* x   = (const float*)d_in[1];
    const float* emb = (const float*)d_in[2];
    float*       out = (float*)d_out;

    dim3 grid(C_N, U_N / 256);   // 64 x 4 = 256 blocks
    dim3 block(TPB);
    content_gather_gemv<<<grid, block, 0, stream>>>(idx, x, emb, out);
}